// Round 2
// baseline (1700.564 us; speedup 1.0000x reference)
//
#include <hip/hip_runtime.h>
#include <math.h>

#define HID 1024
#define VOCAB 32000
#define LAYERS 4
#define MAXLEN 128
#define SPAN 2

// d_out layout (floats): logp [0,64000) | hidden_new [64000,68096) | attn_w [68096,68224)
#define OUT_LOGP 0
#define OUT_HID 64000
#define OUT_ATTNW 68096

// ws layout (floats)
#define WS_XCAT 0       // 3072: emb(2048) | attn_applied(1024)
#define WS_SCORES 3072  // 128
#define WS_X 3200       // 1024 (comb output)
#define WS_GH 4224      // 12288: gh = Whh@h + bhh, all 4 layers
#define WS_RED 16512    // 2000: per-block (max, sumexp), 1000 blocks
#define WS_LOGITS 24576 // 64000
#define WS_BAR 88576    // 2 uints: [cnt, gen]

#define NBLK 1024

__device__ __forceinline__ float dot4(float4 a, float4 b) {
    return a.x * b.x + a.y * b.y + a.z * b.z + a.w * b.w;
}

__device__ __forceinline__ float wave_reduce(float s) {
#pragma unroll
    for (int o = 32; o > 0; o >>= 1) s += __shfl_down(s, o, 64);
    return s;
}

// Generation-counted grid barrier in global memory. Device-scope atomics +
// agent fences (threadfence -> buffer_wbl2/inv on gfx950) give cross-XCD
// visibility of normal stores across the barrier. Bounded spin: never hangs.
__device__ __forceinline__ void gbar(unsigned* bar) {
    __syncthreads();
    if (threadIdx.x == 0) {
        __threadfence();  // release this block's stores
        unsigned gen = __hip_atomic_load(bar + 1, __ATOMIC_RELAXED,
                                         __HIP_MEMORY_SCOPE_AGENT);
        unsigned arrived = __hip_atomic_fetch_add(bar, 1u, __ATOMIC_ACQ_REL,
                                                  __HIP_MEMORY_SCOPE_AGENT) + 1;
        if (arrived == NBLK) {
            __hip_atomic_store(bar, 0u, __ATOMIC_RELAXED,
                               __HIP_MEMORY_SCOPE_AGENT);
            __hip_atomic_fetch_add(bar + 1, 1u, __ATOMIC_RELEASE,
                                   __HIP_MEMORY_SCOPE_AGENT);
        } else {
            unsigned spins = 0;
            while (__hip_atomic_load(bar + 1, __ATOMIC_ACQUIRE,
                                     __HIP_MEMORY_SCOPE_AGENT) == gen) {
                __builtin_amdgcn_s_sleep(4);
                if (++spins > (1u << 22)) break;  // ~0.4s safety valve
            }
        }
        __threadfence();  // acquire remote stores
    }
    __syncthreads();
}

// One fused kernel: grid 1024 x 256 (4 blocks/CU co-resident), 8 grid barriers.
__global__ __launch_bounds__(256, 4) void k_fused(
    const int* __restrict__ ids,
    const float* __restrict__ hidden,
    const float* __restrict__ enc,
    const float* __restrict__ embedding,
    const float* __restrict__ attn_W,
    const float* __restrict__ attn_b,
    const float* __restrict__ comb_W,
    const float* __restrict__ comb_b,
    const float* __restrict__ gru_Wih,
    const float* __restrict__ gru_Whh,
    const float* __restrict__ gru_bih,
    const float* __restrict__ gru_bhh,
    const float* __restrict__ out_W,
    const float* __restrict__ out_b,
    float* __restrict__ out,
    float* __restrict__ ws)
{
    unsigned* bar = (unsigned*)(ws + WS_BAR);
    const int t = threadIdx.x;
    const int lane = t & 63, wv = t >> 6;
    const int blk = blockIdx.x;
    const int gw = blk * 4 + wv;              // global wave id, 0..4095

    __shared__ float sm8[4], ss8[4];
    __shared__ float w2[MAXLEN];
    __shared__ float part[8][32];
    __shared__ float bc[2];
    __shared__ float dred[3][4];

    // ========== Phase A: gh precompute + attn scores + emb gather ==========
    {
        // gh: 12288 rows, 3 per wave.
#pragma unroll
        for (int q = 0; q < 3; q++) {
            int r = gw + 4096 * q;
            int l = r / 3072;
            const float4* W4 = (const float4*)(gru_Whh + (size_t)r * HID);
            const float4* h4 = (const float4*)(hidden + (size_t)l * HID);
            float s = 0.f;
#pragma unroll
            for (int i = 0; i < 4; i++) {
                int k4 = lane + 64 * i;
                s += dot4(W4[k4], h4[k4]);
            }
            s = wave_reduce(s);
            if (lane == 0) ws[WS_GH + r] = s + gru_bhh[r];
        }
        // attn scores: waves 0..127, one row each
        if (gw < MAXLEN) {
            int id0 = ids[0], id1 = ids[1];
            const float4* W4 = (const float4*)(attn_W + (size_t)gw * 3072);
            const float4* e0 = (const float4*)(embedding + (size_t)id0 * HID);
            const float4* e1 = (const float4*)(embedding + (size_t)id1 * HID);
            const float4* h0 = (const float4*)hidden;   // hidden[0]
            float s = 0.f;
#pragma unroll
            for (int i = 0; i < 4; i++) { int k4 = lane + 64 * i; s += dot4(W4[k4], e0[k4]); }
#pragma unroll
            for (int i = 4; i < 8; i++) { int k4 = lane + 64 * i; s += dot4(W4[k4], e1[k4 - 256]); }
#pragma unroll
            for (int i = 8; i < 12; i++) { int k4 = lane + 64 * i; s += dot4(W4[k4], h0[k4 - 512]); }
            s = wave_reduce(s);
            if (lane == 0) ws[WS_SCORES + gw] = s + attn_b[gw];
        }
        // emb gather into xcat[0..2048): blocks 992..999
        if (blk >= 992 && blk < 1000) {
            int idx = (blk - 992) * 256 + t;
            int row = ids[idx >> 10];
            ws[WS_XCAT + idx] = embedding[(size_t)row * HID + (idx & 1023)];
        }
    }
    gbar(bar);

    // ========== Phase B: softmax(128) + attn_applied (blocks 0..31) ==========
    if (blk < 32) {
        if (t < MAXLEN) w2[t] = ws[WS_SCORES + t];
        __syncthreads();
        float m = -INFINITY;
        for (int k = 0; k < MAXLEN; k++) m = fmaxf(m, w2[k]);
        float ssum = 0.f;
        for (int k = 0; k < MAXLEN; k++) ssum += expf(w2[k] - m);
        __syncthreads();
        if (t < MAXLEN) {
            float wt = expf(w2[t] - m) / ssum;
            if (blk == 0) out[OUT_ATTNW + t] = wt;
            w2[t] = wt;
        }
        __syncthreads();
        int col = blk * 32 + (t & 31);
        int seg = t >> 5;
        float p = 0.f;
#pragma unroll
        for (int k = 0; k < 16; k++)
            p += w2[seg * 16 + k] * enc[(size_t)(seg * 16 + k) * HID + col];
        part[seg][t & 31] = p;
        __syncthreads();
        if (t < 32) {
            float acc = 0.f;
#pragma unroll
            for (int s2 = 0; s2 < 8; s2++) acc += part[s2][t];
            ws[WS_XCAT + 2048 + blk * 32 + t] = acc;
        }
    }
    gbar(bar);

    // ========== Phase C: comb matvec + relu (one row per block) ==========
    {
        const float4* W4 = (const float4*)(comb_W + (size_t)blk * 3072);
        const float4* x4 = (const float4*)(ws + WS_XCAT);
        float s = 0.f;
#pragma unroll
        for (int i = 0; i < 3; i++) {
            int k4 = t + 256 * i;
            s += dot4(W4[k4], x4[k4]);
        }
        s = wave_reduce(s);
        if (lane == 0) dred[0][wv] = s;
        __syncthreads();
        if (t == 0) {
            float v = dred[0][0] + dred[0][1] + dred[0][2] + dred[0][3];
            ws[WS_X + blk] = fmaxf(v + comb_b[blk], 0.f);
        }
    }
    gbar(bar);

    // ========== Phases D0..D3: GRU (one unit per block, 4 waves split K) ====
    for (int l = 0; l < LAYERS; l++) {
        {
            int j = blk;
            const float* inp = (l == 0) ? (ws + WS_X) : (out + OUT_HID + (l - 1) * HID);
            const float4* x4 = (const float4*)inp;
            int k4 = wv * 64 + lane;               // this wave's K quarter
            float4 xv = x4[k4];
            const float* Wl = gru_Wih + (size_t)l * 3 * HID * HID;
            float s0 = dot4(((const float4*)(Wl + (size_t)j * HID))[k4], xv);
            float s1 = dot4(((const float4*)(Wl + (size_t)(HID + j) * HID))[k4], xv);
            float s2 = dot4(((const float4*)(Wl + (size_t)(2 * HID + j) * HID))[k4], xv);
#pragma unroll
            for (int o = 32; o > 0; o >>= 1) {
                s0 += __shfl_down(s0, o, 64);
                s1 += __shfl_down(s1, o, 64);
                s2 += __shfl_down(s2, o, 64);
            }
            if (lane == 0) { dred[0][wv] = s0; dred[1][wv] = s1; dred[2][wv] = s2; }
            __syncthreads();
            if (t == 0) {
                const float* bihl = gru_bih + (size_t)l * 3 * HID;
                const float* ghl = ws + WS_GH + (size_t)l * 3 * HID;
                float ir = dred[0][0] + dred[0][1] + dred[0][2] + dred[0][3] + bihl[j];
                float iz = dred[1][0] + dred[1][1] + dred[1][2] + dred[1][3] + bihl[HID + j];
                float in_ = dred[2][0] + dred[2][1] + dred[2][2] + dred[2][3] + bihl[2 * HID + j];
                float rg = 1.f / (1.f + expf(-(ir + ghl[j])));
                float zg = 1.f / (1.f + expf(-(iz + ghl[HID + j])));
                float ng = tanhf(in_ + rg * ghl[2 * HID + j]);
                out[OUT_HID + l * HID + j] =
                    (1.f - zg) * ng + zg * hidden[(size_t)l * HID + j];
            }
        }
        gbar(bar);
    }

    // ========== Phase H: logits, 16 rows/wave as 8 half-wave pairs ==========
    {
        if (gw < 4000) {
            const float* h3 = out + OUT_HID + 3 * HID;
            const int half = lane >> 5;          // 0: even rows, 1: odd rows
            const int l32 = lane & 31;
            const float4* x4 = (const float4*)h3;
            float4 xv[8];
#pragma unroll
            for (int i = 0; i < 8; i++) xv[i] = x4[l32 + 32 * i];
            int r0 = gw * 16;
            float s[8];
#pragma unroll
            for (int p = 0; p < 8; p++) {
                int row = r0 + 2 * p + half;
                const float4* W4 = (const float4*)(out_W + (size_t)row * HID);
                float acc = 0.f;
#pragma unroll
                for (int i = 0; i < 8; i++) acc += dot4(W4[l32 + 32 * i], xv[i]);
                s[p] = acc;
            }
#pragma unroll
            for (int p = 0; p < 8; p++) {
#pragma unroll
                for (int o = 16; o > 0; o >>= 1) s[p] += __shfl_down(s[p], o, 32);
            }
            // lane 0 owns rows r0+2p, lane 32 owns rows r0+2p+1
            float M = -INFINITY, S = 0.f;
            if (l32 == 0) {
#pragma unroll
                for (int p = 0; p < 8; p++) {
                    int row = r0 + 2 * p + half;
                    float v = s[p] + out_b[row];
                    ws[WS_LOGITS + row] = v;
                    if (v > M) { S = S * expf(M - v) + 1.f; M = v; }
                    else S += expf(v - M);
                }
            }
            float Mo = __shfl(M, 32, 64);
            float So = __shfl(S, 32, 64);
            if (lane == 0) {
                float nM = fmaxf(M, Mo);
                S = S * expf(M - nM) + So * expf(Mo - nM);
                sm8[wv] = nM; ss8[wv] = S;
            }
        }
        __syncthreads();
        if (blk < 1000 && t == 0) {
            float M = sm8[0], S = ss8[0];
#pragma unroll
            for (int k = 1; k < 4; k++) {
                float mk = sm8[k], sk = ss8[k];
                if (mk > M) { S = S * expf(M - mk) + sk; M = mk; }
                else S += sk * expf(mk - M);
            }
            ws[WS_RED + blk * 2] = M;
            ws[WS_RED + blk * 2 + 1] = S;
        }
    }
    gbar(bar);

    // ========== Phase I: combine 500 partials/span + logp write ==========
    if (blk < 250) {
        int span = blk / 125;
        float M = -INFINITY, S = 0.f;
#pragma unroll
        for (int k = 0; k < 2; k++) {
            int p = t + 256 * k;
            if (p < 500) {
                float mk = ws[WS_RED + (span * 500 + p) * 2];
                float sk = ws[WS_RED + (span * 500 + p) * 2 + 1];
                if (mk > M) { S = S * expf(M - mk) + sk; M = mk; }
                else S += sk * expf(mk - M);
            }
        }
#pragma unroll
        for (int o = 32; o > 0; o >>= 1) {
            float Mo = __shfl_down(M, o, 64);
            float So = __shfl_down(S, o, 64);
            float nM = fmaxf(M, Mo);
            S = S * expf(M - nM) + So * expf(Mo - nM);
            M = nM;
        }
        if (lane == 0) { sm8[wv] = M; ss8[wv] = S; }
        __syncthreads();
        if (t == 0) {
            float Mf = sm8[0], Sf = ss8[0];
#pragma unroll
            for (int k = 1; k < 4; k++) {
                float mk = sm8[k], sk = ss8[k];
                if (mk > Mf) { Sf = Sf * expf(Mf - mk) + sk; Mf = mk; }
                else Sf += sk * expf(mk - Mf);
            }
            bc[0] = Mf; bc[1] = logf(Sf);
        }
        __syncthreads();
        int i = blk * 256 + t;
        out[OUT_LOGP + i] = ws[WS_LOGITS + i] - bc[0] - bc[1];
    }
}

extern "C" void kernel_launch(void* const* d_in, const int* in_sizes, int n_in,
                              void* d_out, int out_size, void* d_ws, size_t ws_size,
                              hipStream_t stream) {
    const int* ids = (const int*)d_in[0];
    const float* hidden = (const float*)d_in[1];
    const float* enc = (const float*)d_in[2];
    const float* embedding = (const float*)d_in[3];
    const float* attn_W = (const float*)d_in[4];
    const float* attn_b = (const float*)d_in[5];
    const float* comb_W = (const float*)d_in[6];
    const float* comb_b = (const float*)d_in[7];
    const float* gru_Wih = (const float*)d_in[8];
    const float* gru_Whh = (const float*)d_in[9];
    const float* gru_bih = (const float*)d_in[10];
    const float* gru_bhh = (const float*)d_in[11];
    const float* out_W = (const float*)d_in[12];
    const float* out_b = (const float*)d_in[13];
    float* out = (float*)d_out;
    float* ws = (float*)d_ws;

    // zero the grid-barrier state (cnt, gen) for this launch
    hipMemsetAsync((char*)d_ws + (size_t)WS_BAR * 4, 0, 8, stream);

    k_fused<<<NBLK, 256, 0, stream>>>(ids, hidden, enc, embedding, attn_W, attn_b,
                                      comb_W, comb_b, gru_Wih, gru_Whh, gru_bih,
                                      gru_bhh, out_W, out_b, out, ws);
}

// Round 3
// 523.608 us; speedup vs baseline: 3.2478x; 3.2478x over previous
//
#include <hip/hip_runtime.h>
#include <math.h>

#define HID 1024
#define VOCAB 32000
#define LAYERS 4
#define MAXLEN 128
#define SPAN 2

// d_out layout (floats): logp [0,64000) | hidden_new [64000,68096) | attn_w [68096,68224)
#define OUT_LOGP 0
#define OUT_HID 64000
#define OUT_ATTNW 68096

// ws layout (floats)
#define WS_XCAT 0       // 3072: emb(2048) | attn_applied(1024)
#define WS_SCORES 3072  // 128
#define WS_X 3200       // 1024 (comb output)
#define WS_GH 4224      // 12288: gh = Whh@h + bhh, all 4 layers
#define WS_RED 16512    // 2000: per-block (max, sumexp), 1000 blocks
#define WS_LOGITS 24576 // 64000
#define WS_BAR 90112    // barrier region (dwords), 128B aligned

#define NBLK 1024
#define NGRP 64
#define GRPSZ (NBLK / NGRP)     // 16
#define BAR_STRIDE 32           // dwords between slots (128B)
#define PH_SLOTS 129            // 1 root + 64 group + 64 flags
#define PH_DWORDS (PH_SLOTS * BAR_STRIDE)
#define NPHASE 8
#define BAR_DWORDS (PH_DWORDS * NPHASE)

typedef float f32x4 __attribute__((ext_vector_type(4)));

__device__ __forceinline__ float dot4(f32x4 a, f32x4 b) {
    return a[0] * b[0] + a[1] * b[1] + a[2] * b[2] + a[3] * b[3];
}

// ---- coherent (cross-XCD, cache-bypassing) access helpers: no wbl2/inv ever ----
__device__ __forceinline__ f32x4 ldcg4(const f32x4* p) {
    f32x4 v;
    asm volatile("global_load_dwordx4 %0, %1, off sc0 sc1\n\ts_waitcnt vmcnt(0)"
                 : "=v"(v) : "v"(p) : "memory");
    return v;
}
__device__ __forceinline__ float ldcg(const float* p) {
    float v;
    asm volatile("global_load_dword %0, %1, off sc0 sc1\n\ts_waitcnt vmcnt(0)"
                 : "=v"(v) : "v"(p) : "memory");
    return v;
}
__device__ __forceinline__ unsigned ldcgu(const unsigned* p) {
    unsigned v;
    asm volatile("global_load_dword %0, %1, off sc0 sc1\n\ts_waitcnt vmcnt(0)"
                 : "=v"(v) : "v"(p) : "memory");
    return v;
}
__device__ __forceinline__ void stcg(float* p, float v) {
    asm volatile("global_store_dword %0, %1, off sc0 sc1" :: "v"(p), "v"(v) : "memory");
}
__device__ __forceinline__ void stcg4(f32x4* p, f32x4 v) {
    asm volatile("global_store_dwordx4 %0, %1, off sc0 sc1" :: "v"(p), "v"(v) : "memory");
}

__device__ __forceinline__ float wave_reduce(float s) {
#pragma unroll
    for (int o = 32; o > 0; o >>= 1) s += __shfl_down(s, o, 64);
    return s;
}

// Two-level grid barrier, per-phase monotonic counters (no resets, no fences).
// Data visibility comes from sc0sc1 write-through stores (+vmcnt wait before
// arrive) and sc0sc1 loads after — no cache-maintenance ops at all.
__device__ __forceinline__ void gbar(unsigned* barbase, int phase) {
    __syncthreads();
    if (threadIdx.x == 0) {
        asm volatile("s_waitcnt vmcnt(0)" ::: "memory");
        unsigned* base = barbase + (size_t)phase * PH_DWORDS;
        int g = blockIdx.x & (NGRP - 1);
        unsigned* root = base;
        unsigned* gc = base + (1 + g) * BAR_STRIDE;
        unsigned* flag = base + (65 + g) * BAR_STRIDE;
        bool flip = false;
        unsigned ga = __hip_atomic_fetch_add(gc, 1u, __ATOMIC_RELAXED,
                                             __HIP_MEMORY_SCOPE_AGENT) + 1;
        if (ga == GRPSZ) {
            unsigned ra = __hip_atomic_fetch_add(root, 1u, __ATOMIC_RELAXED,
                                                 __HIP_MEMORY_SCOPE_AGENT) + 1;
            if (ra == NGRP) {
                flip = true;
                for (int f = 0; f < NGRP; f++)
                    __hip_atomic_store(base + (65 + f) * BAR_STRIDE, 1u,
                                       __ATOMIC_RELAXED, __HIP_MEMORY_SCOPE_AGENT);
            }
        }
        if (!flip) {
            unsigned it = 0;
            while (ldcgu(flag) == 0u) {
                if (it < 4) __builtin_amdgcn_s_sleep(1);
                else if (it < 32) __builtin_amdgcn_s_sleep(4);
                else __builtin_amdgcn_s_sleep(16);
                if (++it > (1u << 19)) break;  // safety valve: never hangs
            }
        }
    }
    __syncthreads();
}

__global__ __launch_bounds__(256, 4) void k_fused(
    const int* __restrict__ ids,
    const float* __restrict__ hidden,
    const float* __restrict__ enc,
    const float* __restrict__ embedding,
    const float* __restrict__ attn_W,
    const float* __restrict__ attn_b,
    const float* __restrict__ comb_W,
    const float* __restrict__ comb_b,
    const float* __restrict__ gru_Wih,
    const float* __restrict__ gru_Whh,
    const float* __restrict__ gru_bih,
    const float* __restrict__ gru_bhh,
    const float* __restrict__ out_W,
    const float* __restrict__ out_b,
    float* __restrict__ out,
    float* __restrict__ ws)
{
    unsigned* bar = (unsigned*)(ws + WS_BAR);
    const int t = threadIdx.x;
    const int lane = t & 63, wv = t >> 6;
    const int blk = blockIdx.x;
    const int gw = blk * 4 + wv;              // global wave id, 0..4095

    __shared__ float shbuf[3072];
    __shared__ float dred[3][4];
    __shared__ float sm8[4], ss8[4];
    __shared__ float bc[2];

    // ========== Phase 0: gh precompute + attn scores + emb gather ==========
    {
#pragma unroll
        for (int q = 0; q < 3; q++) {
            int r = gw + 4096 * q;
            int l = r / 3072;
            const f32x4* W4 = (const f32x4*)(gru_Whh + (size_t)r * HID);
            const f32x4* h4 = (const f32x4*)(hidden + (size_t)l * HID);
            float s = 0.f;
#pragma unroll
            for (int i = 0; i < 4; i++) {
                int k4 = lane + 64 * i;
                s += dot4(W4[k4], h4[k4]);
            }
            s = wave_reduce(s);
            if (lane == 0) stcg(&ws[WS_GH + r], s + gru_bhh[r]);
        }
        if (gw < MAXLEN) {
            int id0 = ids[0], id1 = ids[1];
            const f32x4* W4 = (const f32x4*)(attn_W + (size_t)gw * 3072);
            const f32x4* e0 = (const f32x4*)(embedding + (size_t)id0 * HID);
            const f32x4* e1 = (const f32x4*)(embedding + (size_t)id1 * HID);
            const f32x4* h0 = (const f32x4*)hidden;   // hidden[0]
            float s = 0.f;
#pragma unroll
            for (int i = 0; i < 4; i++) { int k4 = lane + 64 * i; s += dot4(W4[k4], e0[k4]); }
#pragma unroll
            for (int i = 4; i < 8; i++) { int k4 = lane + 64 * i; s += dot4(W4[k4], e1[k4 - 256]); }
#pragma unroll
            for (int i = 8; i < 12; i++) { int k4 = lane + 64 * i; s += dot4(W4[k4], h0[k4 - 512]); }
            s = wave_reduce(s);
            if (lane == 0) stcg(&ws[WS_SCORES + gw], s + attn_b[gw]);
        }
        // emb gather: blocks 992,993 write xcat[0..2048) as float4
        if (blk == 992 || blk == 993) {
            int e = ((blk - 992) * 256 + t) * 4;    // 0..2044, step 4
            int row = ids[e >> 10];
            f32x4 v = *(const f32x4*)(embedding + (size_t)row * HID + (e & 1023));
            stcg4((f32x4*)(ws + WS_XCAT + e), v);
        }
    }
    gbar(bar, 0);

    // ========== Phase 1: softmax(128) + attn_applied (blocks 0..31) ==========
    if (blk < 32) {
        float* w2 = shbuf;                       // [128]
        float (*part)[32] = (float(*)[32])(shbuf + 128);
        if (t < MAXLEN) w2[t] = ldcg(&ws[WS_SCORES + t]);
        __syncthreads();
        float m = -INFINITY;
        for (int k = 0; k < MAXLEN; k++) m = fmaxf(m, w2[k]);
        float ssum = 0.f;
        for (int k = 0; k < MAXLEN; k++) ssum += expf(w2[k] - m);
        __syncthreads();
        if (t < MAXLEN) {
            float wt = expf(w2[t] - m) / ssum;
            if (blk == 0) out[OUT_ATTNW + t] = wt;
            w2[t] = wt;
        }
        __syncthreads();
        int col = blk * 32 + (t & 31);
        int seg = t >> 5;
        float p = 0.f;
#pragma unroll
        for (int k = 0; k < 16; k++)
            p += w2[seg * 16 + k] * enc[(size_t)(seg * 16 + k) * HID + col];
        part[seg][t & 31] = p;
        __syncthreads();
        if (t < 32) {
            float acc = 0.f;
#pragma unroll
            for (int s2 = 0; s2 < 8; s2++) acc += part[s2][t];
            stcg(&ws[WS_XCAT + 2048 + blk * 32 + t], acc);
        }
    }
    gbar(bar, 1);

    // ========== Phase 2: comb matvec + relu (blocks 0..255, 1 row/wave) ======
    if (blk < 256) {
        f32x4* sh4 = (f32x4*)shbuf;              // xcat staged: 768 f32x4
        const f32x4* xc4 = (const f32x4*)(ws + WS_XCAT);
#pragma unroll
        for (int i = 0; i < 3; i++) sh4[t + 256 * i] = ldcg4(xc4 + t + 256 * i);
        __syncthreads();
        int r = blk * 4 + wv;
        const f32x4* W4 = (const f32x4*)(comb_W + (size_t)r * 3072);
        float s = 0.f;
#pragma unroll
        for (int i = 0; i < 12; i++) {
            int k4 = lane + 64 * i;
            s += dot4(W4[k4], sh4[k4]);
        }
        s = wave_reduce(s);
        if (lane == 0) stcg(&ws[WS_X + r], fmaxf(s + comb_b[r], 0.f));
    }
    gbar(bar, 2);

    // ========== Phases 3..6: GRU (one unit per block, 4 waves split K) ========
    for (int l = 0; l < LAYERS; l++) {
        {
            int j = blk;
            const float* inp = (l == 0) ? (ws + WS_X) : (out + OUT_HID + (l - 1) * HID);
            f32x4* sh4 = (f32x4*)shbuf;          // inp staged: 256 f32x4
            sh4[t] = ldcg4((const f32x4*)inp + t);
            __syncthreads();
            int k4 = wv * 64 + lane;
            f32x4 xv = sh4[k4];
            const float* Wl = gru_Wih + (size_t)l * 3 * HID * HID;
            float s0 = dot4(((const f32x4*)(Wl + (size_t)j * HID))[k4], xv);
            float s1 = dot4(((const f32x4*)(Wl + (size_t)(HID + j) * HID))[k4], xv);
            float s2 = dot4(((const f32x4*)(Wl + (size_t)(2 * HID + j) * HID))[k4], xv);
#pragma unroll
            for (int o = 32; o > 0; o >>= 1) {
                s0 += __shfl_down(s0, o, 64);
                s1 += __shfl_down(s1, o, 64);
                s2 += __shfl_down(s2, o, 64);
            }
            if (lane == 0) { dred[0][wv] = s0; dred[1][wv] = s1; dred[2][wv] = s2; }
            __syncthreads();
            if (t == 0) {
                const float* bihl = gru_bih + (size_t)l * 3 * HID;
                const float* ghl = ws + WS_GH + (size_t)l * 3 * HID;
                float ir = dred[0][0] + dred[0][1] + dred[0][2] + dred[0][3] + bihl[j];
                float iz = dred[1][0] + dred[1][1] + dred[1][2] + dred[1][3] + bihl[HID + j];
                float in_ = dred[2][0] + dred[2][1] + dred[2][2] + dred[2][3] + bihl[2 * HID + j];
                float rg = 1.f / (1.f + expf(-(ir + ldcg(&ghl[j]))));
                float zg = 1.f / (1.f + expf(-(iz + ldcg(&ghl[HID + j]))));
                float ng = tanhf(in_ + rg * ldcg(&ghl[2 * HID + j]));
                stcg(&out[OUT_HID + l * HID + j],
                     (1.f - zg) * ng + zg * hidden[(size_t)l * HID + j]);
            }
            __syncthreads();   // protect shbuf reuse across layers
        }
        gbar(bar, 3 + l);
    }

    // ========== Phase 7: logits, 16 rows/wave as 8 half-wave pairs ==========
    {
        if (blk < 1000) {
            f32x4* sh4 = (f32x4*)shbuf;          // h3 staged: 256 f32x4
            sh4[t] = ldcg4((const f32x4*)(out + OUT_HID + 3 * HID) + t);
            __syncthreads();
            const int half = lane >> 5;          // 0: even rows, 1: odd rows
            const int l32 = lane & 31;
            f32x4 xv[8];
#pragma unroll
            for (int i = 0; i < 8; i++) xv[i] = sh4[l32 + 32 * i];
            int r0 = gw * 16;
            float s[8];
#pragma unroll
            for (int p = 0; p < 8; p++) {
                int row = r0 + 2 * p + half;
                const f32x4* W4 = (const f32x4*)(out_W + (size_t)row * HID);
                float acc = 0.f;
#pragma unroll
                for (int i = 0; i < 8; i++) acc += dot4(W4[l32 + 32 * i], xv[i]);
                s[p] = acc;
            }
#pragma unroll
            for (int p = 0; p < 8; p++) {
#pragma unroll
                for (int o = 16; o > 0; o >>= 1) s[p] += __shfl_down(s[p], o, 32);
            }
            float M = -INFINITY, S = 0.f;
            if (l32 == 0) {
#pragma unroll
                for (int p = 0; p < 8; p++) {
                    int row = r0 + 2 * p + half;
                    float v = s[p] + out_b[row];
                    stcg(&ws[WS_LOGITS + row], v);
                    if (v > M) { S = S * expf(M - v) + 1.f; M = v; }
                    else S += expf(v - M);
                }
            }
            float Mo = __shfl(M, 32, 64);
            float So = __shfl(S, 32, 64);
            if (lane == 0) {
                float nM = fmaxf(M, Mo);
                S = S * expf(M - nM) + So * expf(Mo - nM);
                sm8[wv] = nM; ss8[wv] = S;
            }
            __syncthreads();
            if (t == 0) {
                float M2 = sm8[0], S2 = ss8[0];
#pragma unroll
                for (int k = 1; k < 4; k++) {
                    float mk = sm8[k], sk = ss8[k];
                    if (mk > M2) { S2 = S2 * expf(M2 - mk) + sk; M2 = mk; }
                    else S2 += sk * expf(mk - M2);
                }
                stcg(&ws[WS_RED + blk * 2], M2);
                stcg(&ws[WS_RED + blk * 2 + 1], S2);
            }
        }
    }
    gbar(bar, 7);

    // ========== Phase 8: combine 500 partials/span + logp write ==========
    if (blk < 250) {
        int span = blk / 125;
        float M = -INFINITY, S = 0.f;
#pragma unroll
        for (int k = 0; k < 2; k++) {
            int p = t + 256 * k;
            if (p < 500) {
                float mk = ldcg(&ws[WS_RED + (span * 500 + p) * 2]);
                float sk = ldcg(&ws[WS_RED + (span * 500 + p) * 2 + 1]);
                if (mk > M) { S = S * expf(M - mk) + sk; M = mk; }
                else S += sk * expf(mk - M);
            }
        }
#pragma unroll
        for (int o = 32; o > 0; o >>= 1) {
            float Mo = __shfl_down(M, o, 64);
            float So = __shfl_down(S, o, 64);
            float nM = fmaxf(M, Mo);
            S = S * expf(M - nM) + So * expf(Mo - nM);
            M = nM;
        }
        if (lane == 0) { sm8[wv] = M; ss8[wv] = S; }
        __syncthreads();
        if (t == 0) {
            float Mf = sm8[0], Sf = ss8[0];
#pragma unroll
            for (int k = 1; k < 4; k++) {
                float mk = sm8[k], sk = ss8[k];
                if (mk > Mf) { Sf = Sf * expf(Mf - mk) + sk; Mf = mk; }
                else Sf += sk * expf(mk - Mf);
            }
            bc[0] = Mf; bc[1] = logf(Sf);
        }
        __syncthreads();
        int i = blk * 256 + t;
        out[OUT_LOGP + i] = ldcg(&ws[WS_LOGITS + i]) - bc[0] - bc[1];
    }
}

extern "C" void kernel_launch(void* const* d_in, const int* in_sizes, int n_in,
                              void* d_out, int out_size, void* d_ws, size_t ws_size,
                              hipStream_t stream) {
    const int* ids = (const int*)d_in[0];
    const float* hidden = (const float*)d_in[1];
    const float* enc = (const float*)d_in[2];
    const float* embedding = (const float*)d_in[3];
    const float* attn_W = (const float*)d_in[4];
    const float* attn_b = (const float*)d_in[5];
    const float* comb_W = (const float*)d_in[6];
    const float* comb_b = (const float*)d_in[7];
    const float* gru_Wih = (const float*)d_in[8];
    const float* gru_Whh = (const float*)d_in[9];
    const float* gru_bih = (const float*)d_in[10];
    const float* gru_bhh = (const float*)d_in[11];
    const float* out_W = (const float*)d_in[12];
    const float* out_b = (const float*)d_in[13];
    float* out = (float*)d_out;
    float* ws = (float*)d_ws;

    // zero the per-phase barrier counters/flags for this launch
    hipMemsetAsync((char*)d_ws + (size_t)WS_BAR * 4, 0, (size_t)BAR_DWORDS * 4, stream);

    k_fused<<<NBLK, 256, 0, stream>>>(ids, hidden, enc, embedding, attn_W, attn_b,
                                      comb_W, comb_b, gru_Wih, gru_Whh, gru_bih,
                                      gru_bhh, out_W, out_b, out, ws);
}